// Round 6
// baseline (780.994 us; speedup 1.0000x reference)
//
#include <hip/hip_runtime.h>
#include <hip/hip_bf16.h>

#define MNBR 32
#define FDIM 64

typedef __attribute__((ext_vector_type(8))) short bf16x8;
typedef __attribute__((ext_vector_type(16))) float f32x16;
typedef __attribute__((ext_vector_type(4))) float f32x4;
typedef __attribute__((ext_vector_type(4))) float fvec4;

static __device__ __forceinline__ unsigned short f2bf(float x) {
    unsigned u = __builtin_bit_cast(unsigned, x);
    u += 0x7FFFu + ((u >> 16) & 1u);   // RNE
    return (unsigned short)(u >> 16);
}
static __device__ __forceinline__ bf16x8 pack8(fvec4 a, fvec4 b) {
    bf16x8 r;
    r[0] = (short)f2bf(a[0]); r[1] = (short)f2bf(a[1]);
    r[2] = (short)f2bf(a[2]); r[3] = (short)f2bf(a[3]);
    r[4] = (short)f2bf(b[0]); r[5] = (short)f2bf(b[1]);
    r[6] = (short)f2bf(b[2]); r[7] = (short)f2bf(b[3]);
    return r;
}
static __device__ __forceinline__ float sigmoid_f(float x) {
    return __builtin_amdgcn_rcpf(1.f + __expf(-x));
}
static __device__ __forceinline__ float softplus_f(float x) {
    return fmaxf(x, 0.f) + __logf(1.f + __expf(-fabsf(x)));
}

// ---------------------------------------------------------------------------
// Kernel P: (a) node f32 -> nodeBF bf16, (b) A_pk[n][c32*4+q] = W_self·node+b
//           in epilogue-packed layout (q: o = q<2 ? q*32+c32 : 64+(q-2)*32+c32
//           i.e. addr = n*128 + (o&31)*4 + (o>>5)), (c) block 0 packs W-frags
//           (nbr+edge cols, 32x32x16 B-operand layout) into ws for kernel E.
// One wave per 16-node tile; W_self frags in registers (one-time load).
// ---------------------------------------------------------------------------
__global__ __launch_bounds__(256) void prep_kernel(
    const float* __restrict__ node, const float* __restrict__ W,
    const float* __restrict__ b, float* __restrict__ A_pk,
    short* __restrict__ nodeBF, short* __restrict__ Wfrag, int n_nodes)
{
    const int lane = threadIdx.x & 63;
    const int w    = threadIdx.x >> 6;
    const int c = lane & 15, g = lane >> 4;

    // ---- block 0: pack W fragments for edge kernel ----
    if (blockIdx.x == 0) {
        const int c32 = lane & 31, hi = lane >> 5;
        for (int fi = w; fi < 32; fi += 4) {       // fi = t*8 + s
            int t = fi >> 3, s = fi & 7;
            int o = t * 32 + c32;                  // output col 0..127
            // fused K: k 0..63 = edge cols (W col 128+k), 64..127 = nbr (W col 64+..)
            int kcol = (s < 4) ? (128 + s * 16 + hi * 8)
                               : (64 + (s - 4) * 16 + hi * 8);
            const float* wp = W + (size_t)o * 192 + kcol;
            bf16x8 fr;
            #pragma unroll
            for (int j = 0; j < 8; ++j) fr[j] = (short)f2bf(wp[j]);
            *(bf16x8*)(Wfrag + ((size_t)fi * 64 + lane) * 8) = fr;
        }
    }

    // ---- W_self frags (16x16x32 B-operand): t 0..7 (o=t*16+c), s 0..1 ----
    bf16x8 Wsf[8][2];
    float bias[8];
    #pragma unroll
    for (int t = 0; t < 8; ++t) {
        const int o = t * 16 + c;
        bias[t] = b[o];
        #pragma unroll
        for (int s = 0; s < 2; ++s) {
            const float* wp = W + (size_t)o * 192 + s * 32 + g * 8;
            fvec4 w0 = *(const fvec4*)(wp);
            fvec4 w1 = *(const fvec4*)(wp + 4);
            Wsf[t][s] = pack8(w0, w1);
        }
    }

    const int ntiles = (n_nodes + 15) >> 4;        // 3125 (exact: 50000=16*3125)
    for (int rt = blockIdx.x * 4 + w; rt < ntiles; rt += gridDim.x * 4) {
        const int row = rt * 16 + c;
        const float* p = node + (size_t)row * FDIM + g * 8;
        fvec4 e0 = *(const fvec4*)(p);
        fvec4 e1 = *(const fvec4*)(p + 4);
        fvec4 e2 = *(const fvec4*)(p + 32);
        fvec4 e3 = *(const fvec4*)(p + 36);
        bf16x8 af0 = pack8(e0, e1);                // k = g*8..g*8+7
        bf16x8 af1 = pack8(e2, e3);                // k = 32+g*8..+7
        // emit bf16 node copy (exact frags the edge kernel will gather)
        *(bf16x8*)(nodeBF + (size_t)row * FDIM + g * 8)      = af0;
        *(bf16x8*)(nodeBF + (size_t)row * FDIM + 32 + g * 8) = af1;

        f32x4 acc[8];
        #pragma unroll
        for (int t = 0; t < 8; ++t) acc[t] = (f32x4){0.f, 0.f, 0.f, 0.f};
        #pragma unroll
        for (int t = 0; t < 8; ++t) {
            acc[t] = __builtin_amdgcn_mfma_f32_16x16x32_bf16(af0, Wsf[t][0], acc[t], 0, 0, 0);
            acc[t] = __builtin_amdgcn_mfma_f32_16x16x32_bf16(af1, Wsf[t][1], acc[t], 0, 0, 0);
        }
        #pragma unroll
        for (int t = 0; t < 8; ++t) {
            const int o = t * 16 + c;
            const size_t base = ((size_t)(o & 31)) * 4 + (o >> 5);
            #pragma unroll
            for (int r = 0; r < 4; ++r) {          // D: row = g*4+r, col = c
                int n = rt * 16 + g * 4 + r;
                A_pk[(size_t)n * 128 + base] = acc[t][r] + bias[t];
            }
        }
    }
}

// ---------------------------------------------------------------------------
// Kernel E: one wave per node. 32x32x16 MFMA, M=32 edges, N=128 outputs
// (4 tiles), K=128 fused (edge 64 + gathered-nbr 64). W-frags from LDS.
// Epilogue: gf/gc from acc + packed A row, sigmoid*softplus, mask, reduce.
// ---------------------------------------------------------------------------
__global__ __launch_bounds__(256) void edge_fused(
    const float* __restrict__ node, const float* __restrict__ edge,
    const int* __restrict__ eidx, const float* __restrict__ A_pk,
    const short* __restrict__ nodeBF, const short* __restrict__ Wfrag,
    const float* __restrict__ alphap, float* __restrict__ out, int n_nodes)
{
    __shared__ short sW[32 * 64 * 8];              // 32 KB: [fi=t*8+s][lane] bf16x8
    for (int i = threadIdx.x; i < 32 * 64; i += 256)
        *(bf16x8*)(sW + (size_t)i * 8) = *(const bf16x8*)(Wfrag + (size_t)i * 8);
    __syncthreads();

    const int lane = threadIdx.x & 63;
    const int w    = threadIdx.x >> 6;
    const int c32 = lane & 31, hi = lane >> 5;
    const float alpha = alphap[0];

    for (int n = blockIdx.x * 4 + w; n < n_nodes; n += gridDim.x * 4) {
        // issue the dependent chain first: eidx -> nbr gathers
        const int j = eidx[(size_t)n * MNBR + c32];
        const int jsafe = (j < 0) ? 0 : j;

        // independent loads: packed A row, self-node feature, edge rows
        const fvec4 aq = *(const fvec4*)(A_pk + (size_t)n * 128 + c32 * 4);
        const float ns = node[(size_t)n * FDIM + lane];

        const float* ep = edge + ((size_t)n * MNBR + c32) * FDIM + hi * 8;
        bf16x8 ea[4];
        #pragma unroll
        for (int s = 0; s < 4; ++s) {              // k = s*16 + hi*8 + j
            fvec4 x0 = __builtin_nontemporal_load((const fvec4*)(ep + s * 16));
            fvec4 x1 = __builtin_nontemporal_load((const fvec4*)(ep + s * 16 + 4));
            ea[s] = pack8(x0, x1);
        }
        const short* np_ = nodeBF + (size_t)jsafe * FDIM + hi * 8;
        bf16x8 na[4];
        #pragma unroll
        for (int s = 0; s < 4; ++s)
            na[s] = *(const bf16x8*)(np_ + s * 16);

        f32x16 acc[4] = {};
        #pragma unroll
        for (int s = 0; s < 8; ++s) {
            const bf16x8 afr = (s < 4) ? ea[s] : na[s - 4];
            #pragma unroll
            for (int t = 0; t < 4; ++t) {
                bf16x8 wf = *(const bf16x8*)(sW + ((size_t)(t * 8 + s) * 64 + lane) * 8);
                acc[t] = __builtin_amdgcn_mfma_f32_32x32x16_bf16(afr, wf, acc[t], 0, 0, 0);
            }
        }

        // epilogue: o(t) = t*32 + c32; filter tiles t=0,1 pair with core t+2
        float nsum0 = 0.f, nsum1 = 0.f;
        #pragma unroll
        for (int r = 0; r < 16; ++r) {
            const int row = (r & 3) + 8 * (r >> 2) + 4 * hi;   // edge index
            const int jr = __shfl(j, row, 32);
            const float m = (jr >= 0) ? 1.f : 0.f;
            float gf0 = acc[0][r] + aq[0], gc0 = acc[2][r] + aq[2];
            float gf1 = acc[1][r] + aq[1], gc1 = acc[3][r] + aq[3];
            nsum0 += m * (sigmoid_f(gf0) * softplus_f(gc0));
            nsum1 += m * (sigmoid_f(gf1) * softplus_f(gc1));
        }
        nsum0 += __shfl_xor(nsum0, 32);
        nsum1 += __shfl_xor(nsum1, 32);
        const float v = hi ? nsum1 : nsum0;        // lane's feature o = lane
        out[(size_t)n * FDIM + lane] = softplus_f(fmaf(alpha, ns, v));
    }
}

extern "C" void kernel_launch(void* const* d_in, const int* in_sizes, int n_in,
                              void* d_out, int out_size, void* d_ws, size_t ws_size,
                              hipStream_t stream) {
    const float* node  = (const float*)d_in[0];
    const float* edge  = (const float*)d_in[1];
    const int*   eidx  = (const int*)d_in[2];
    const float* W     = (const float*)d_in[3];
    const float* b     = (const float*)d_in[4];
    const float* alpha = (const float*)d_in[5];
    float* out = (float*)d_out;

    const int n_nodes = in_sizes[0] / FDIM;        // 50000

    char* ws = (char*)d_ws;
    short* nodeBF = (short*)ws;                                  // 6.4 MB
    float* A_pk   = (float*)(ws + (size_t)n_nodes * FDIM * 2);   // 25.6 MB
    short* Wfrag  = (short*)(ws + (size_t)n_nodes * FDIM * 2
                                + (size_t)n_nodes * 128 * 4);    // 32 KB

    const int ntiles = (n_nodes + 15) >> 4;        // 3125
    prep_kernel<<<(ntiles + 3) / 4, 256, 0, stream>>>(node, W, b, A_pk, nodeBF,
                                                      Wfrag, n_nodes);
    edge_fused<<<2048, 256, 0, stream>>>(node, edge, eidx, A_pk, nodeBF, Wfrag,
                                         alpha, out, n_nodes);
}